// Round 1
// baseline (474.732 us; speedup 1.0000x reference)
//
#include <hip/hip_runtime.h>

#define D 128
#define ROWS_PER_BLOCK 64

// ---- 1. histogram of dst ----
__global__ void hist_k(const int* __restrict__ dst, int nE, int* __restrict__ hist) {
    int i = blockIdx.x * blockDim.x + threadIdx.x;
    if (i < nE) atomicAdd(&hist[dst[i]], 1);
}

// ---- 2. exclusive scan of hist -> offsets (and cursor copy), single block ----
__global__ void scan_k(const int* __restrict__ hist, int n,
                       int* __restrict__ offsets, int* __restrict__ cursor) {
    __shared__ int buf[1024];
    __shared__ int carry;
    if (threadIdx.x == 0) carry = 0;
    __syncthreads();
    for (int base = 0; base < n; base += 1024) {
        int i = base + threadIdx.x;
        int v = (i < n) ? hist[i] : 0;
        buf[threadIdx.x] = v;
        __syncthreads();
        // Hillis-Steele inclusive scan
        for (int off = 1; off < 1024; off <<= 1) {
            int t = (threadIdx.x >= off) ? buf[threadIdx.x - off] : 0;
            __syncthreads();
            buf[threadIdx.x] += t;
            __syncthreads();
        }
        int incl = buf[threadIdx.x];
        int excl = incl - v;
        if (i < n) { offsets[i] = carry + excl; cursor[i] = carry + excl; }
        __syncthreads();
        if (threadIdx.x == 1023) carry += buf[1023];
        __syncthreads();
    }
    if (threadIdx.x == 1023) offsets[n] = carry;  // == nE
}

// ---- 3. scatter src ids into dst-buckets ----
__global__ void scatter_k(const int* __restrict__ src, const int* __restrict__ dst,
                          int nE, int* __restrict__ cursor, int* __restrict__ eidx) {
    int i = blockIdx.x * blockDim.x + threadIdx.x;
    if (i < nE) {
        int p = atomicAdd(&cursor[dst[i]], 1);
        eidx[p] = src[i];
    }
}

// ---- 4. wave-per-node segment sum: s[i] = sum_{e: dst=i} x[src_e] ----
__global__ void segsum_k(const float* __restrict__ x, const int* __restrict__ offsets,
                         const int* __restrict__ eidx, float* __restrict__ s, int nNodes) {
    int wave = (int)((blockIdx.x * (unsigned)blockDim.x + threadIdx.x) >> 6);
    int lane = threadIdx.x & 63;
    if (wave >= nNodes) return;
    int beg = offsets[wave];
    int end = offsets[wave + 1];
    float2 acc = make_float2(0.f, 0.f);
    for (int k = beg; k < end; ++k) {
        int j = eidx[k];
        float2 v = ((const float2*)(x + (size_t)j * D))[lane];
        acc.x += v.x; acc.y += v.y;
    }
    ((float2*)(s + (size_t)wave * D))[lane] = acc;
}

// ---- 5. out = relu(x@W + s@M), register-resident matrix columns ----
__global__ __launch_bounds__(256) void gemm_k(const float* __restrict__ x,
                                              const float* __restrict__ s,
                                              const float* __restrict__ W,
                                              const float* __restrict__ M,
                                              float* __restrict__ out, int nNodes) {
    __shared__ float xrow[D];
    __shared__ float srow[D];
    __shared__ float bpart[D];
    int tid = threadIdx.x;
    int half = tid >> 7;          // 0 -> W half, 1 -> M half
    int col = tid & (D - 1);
    const float* mat = half ? M : W;
    float c[D];
#pragma unroll
    for (int k = 0; k < D; ++k) c[k] = mat[k * D + col];

    int row0 = blockIdx.x * ROWS_PER_BLOCK;
    int rowEnd = row0 + ROWS_PER_BLOCK;
    if (rowEnd > nNodes) rowEnd = nNodes;
    for (int r = row0; r < rowEnd; ++r) {
        if (tid < D) xrow[tid] = x[(size_t)r * D + tid];
        else         srow[col] = s[(size_t)r * D + col];
        __syncthreads();
        const float* vec = half ? srow : xrow;
        float acc = 0.f;
#pragma unroll
        for (int k4 = 0; k4 < D / 4; ++k4) {
            float4 v = ((const float4*)vec)[k4];
            acc += v.x * c[4 * k4 + 0];
            acc += v.y * c[4 * k4 + 1];
            acc += v.z * c[4 * k4 + 2];
            acc += v.w * c[4 * k4 + 3];
        }
        if (half) bpart[col] = acc;
        __syncthreads();
        if (!half) {
            float v = acc + bpart[col];
            out[(size_t)r * D + col] = v > 0.f ? v : 0.f;
        }
        __syncthreads();
    }
}

extern "C" void kernel_launch(void* const* d_in, const int* in_sizes, int n_in,
                              void* d_out, int out_size, void* d_ws, size_t ws_size,
                              hipStream_t stream) {
    const float* x = (const float*)d_in[0];
    const float* W = (const float*)d_in[1];
    const float* M = (const float*)d_in[2];
    const int* edges = (const int*)d_in[3];

    int N  = in_sizes[0] / D;        // 50000
    int nE = in_sizes[3] / 2;        // 800000
    const int* src = edges;          // edges[0, :]
    const int* dst = edges + nE;     // edges[1, :]
    float* out = (float*)d_out;

    // workspace layout
    char* w = (char*)d_ws;
    float* s = (float*)w;            w += (size_t)N * D * sizeof(float);   // 25.6 MB
    int* hist = (int*)w;             w += (size_t)(N + 1) * sizeof(int);
    int* offsets = (int*)w;          w += (size_t)(N + 1) * sizeof(int);
    int* cursor = (int*)w;           w += (size_t)(N + 1) * sizeof(int);
    int* eidx = (int*)w;             w += (size_t)nE * sizeof(int);        // 3.2 MB

    hipMemsetAsync(hist, 0, (size_t)N * sizeof(int), stream);

    hist_k<<<(nE + 255) / 256, 256, 0, stream>>>(dst, nE, hist);
    scan_k<<<1, 1024, 0, stream>>>(hist, N, offsets, cursor);
    scatter_k<<<(nE + 255) / 256, 256, 0, stream>>>(src, dst, nE, cursor, eidx);

    int segBlocks = (N * 64 + 255) / 256;        // one wave per node
    segsum_k<<<segBlocks, 256, 0, stream>>>(x, offsets, eidx, s, N);

    int gemmBlocks = (N + ROWS_PER_BLOCK - 1) / ROWS_PER_BLOCK;
    gemm_k<<<gemmBlocks, 256, 0, stream>>>(x, s, W, M, out, N);
}

// Round 2
// 309.923 us; speedup vs baseline: 1.5318x; 1.5318x over previous
//
#include <hip/hip_runtime.h>

#define D 128
#define NTHREADS 256

// ---------- 1. histogram of dst ----------
__global__ void hist_k(const int* __restrict__ dst, int nE, int* __restrict__ hist) {
    int i = blockIdx.x * blockDim.x + threadIdx.x;
    if (i < nE) atomicAdd(&hist[dst[i]], 1);
}

// ---------- 2. reserve bucket ranges: block scan + single atomic bump ----------
// Bucket ORDER in eidx is irrelevant; only contiguity per dst matters. So no
// global exclusive scan needed — each block reserves its total via one atomic.
__global__ void reserve_k(const int* __restrict__ hist, int n,
                          int* __restrict__ beg, int* __restrict__ cursor,
                          int* __restrict__ total) {
    __shared__ int wsum[4];
    __shared__ int sbase;
    int i = blockIdx.x * NTHREADS + threadIdx.x;
    int v = (i < n) ? hist[i] : 0;
    int lane = threadIdx.x & 63;
    int wid  = threadIdx.x >> 6;
    int incl = v;
#pragma unroll
    for (int off = 1; off < 64; off <<= 1) {
        int t = __shfl_up(incl, off, 64);
        if (lane >= off) incl += t;
    }
    if (lane == 63) wsum[wid] = incl;
    __syncthreads();
    if (threadIdx.x == 0)
        sbase = atomicAdd(total, wsum[0] + wsum[1] + wsum[2] + wsum[3]);
    __syncthreads();
    int wbase = sbase;
    for (int w = 0; w < wid; ++w) wbase += wsum[w];
    int excl = wbase + incl - v;
    if (i < n) { beg[i] = excl; cursor[i] = excl; }
}

// ---------- 3. scatter src ids into dst-buckets ----------
__global__ void scatter_k(const int* __restrict__ src, const int* __restrict__ dst,
                          int nE, int* __restrict__ cursor, int* __restrict__ eidx) {
    int i = blockIdx.x * blockDim.x + threadIdx.x;
    if (i < nE) {
        int p = atomicAdd(&cursor[dst[i]], 1);
        eidx[p] = src[i];
    }
}

// ---------- 4. wave-per-node segment sum: s[i] = sum_{e: dst=i} x[src_e] ----------
__global__ void segsum_k(const float* __restrict__ x, const int* __restrict__ beg,
                         const int* __restrict__ hist, const int* __restrict__ eidx,
                         float* __restrict__ s, int nNodes) {
    int wave = (int)((blockIdx.x * (unsigned)blockDim.x + threadIdx.x) >> 6);
    int lane = threadIdx.x & 63;
    if (wave >= nNodes) return;
    int b = beg[wave];
    int e = b + hist[wave];
    float2 acc = make_float2(0.f, 0.f);
    for (int k = b; k < e; ++k) {
        int j = eidx[k];
        float2 v = ((const float2*)(x + (size_t)j * D))[lane];
        acc.x += v.x; acc.y += v.y;
    }
    ((float2*)(s + (size_t)wave * D))[lane] = acc;
}

// ---------- 5. out = relu([x|s] @ [W;M]) — tiled register-blocked GEMM ----------
// M=50000 rows, N=128 cols, K=256 (k<128 -> x@W part, k>=128 -> s@M part).
// BM=64, BN=128, BK=32, 256 threads, per-thread micro-tile 8x4.
// As stored k-major with XOR swizzle m^((k>>2)<<3): transpose ds_writes land
// 2 lanes/bank (free), fragment reads stay b128-contiguous.
__global__ __launch_bounds__(NTHREADS) void gemm2_k(
    const float* __restrict__ x, const float* __restrict__ s,
    const float* __restrict__ W, const float* __restrict__ M,
    float* __restrict__ out, int nNodes)
{
    __shared__ float As[32][64];    // [k][m swizzled]
    __shared__ float Bs[32][128];   // [k][n] linear
    const int tid  = threadIdx.x;
    const int tx   = tid & 31;      // col group: cols tx*4 .. tx*4+3
    const int ty   = tid >> 5;      // row group: rows ty*8 .. ty*8+7
    const int row0 = blockIdx.x * 64;

    float acc[8][4];
#pragma unroll
    for (int i = 0; i < 8; ++i)
#pragma unroll
        for (int j = 0; j < 4; ++j) acc[i][j] = 0.f;

    for (int kt = 0; kt < 8; ++kt) {
        const int kb = kt * 32;
        const float* Asrc = (kb < 128) ? x : s;
        const float* Bsrc = (kb < 128) ? W : M;
        const int ak = kb & 127;

        // register-stage A (64 rows x 32 k, float4 per thread x2)
        float4 av[2];
        int mm[2], kk4[2];
#pragma unroll
        for (int it = 0; it < 2; ++it) {
            int q = tid + it * 256;           // 0..511
            int m = q >> 3, k4 = q & 7;       // m 0..63, k4 0..7
            mm[it] = m; kk4[it] = k4;
            int r = row0 + m;
            float4 v = make_float4(0.f, 0.f, 0.f, 0.f);
            if (r < nNodes) v = ((const float4*)(Asrc + (size_t)r * D + ak))[k4];
            av[it] = v;
        }
        // register-stage B (32 rows x 128, fully coalesced)
        float4 bv[4];
#pragma unroll
        for (int it = 0; it < 4; ++it) {
            int q = tid + it * 256;           // 0..1023
            bv[it] = ((const float4*)(Bsrc + (size_t)ak * D))[q];
        }

        __syncthreads();   // previous iteration's compute done before overwrite

#pragma unroll
        for (int it = 0; it < 2; ++it) {
            int msw = mm[it] ^ (kk4[it] << 3);
            int kk  = kk4[it] * 4;
            As[kk + 0][msw] = av[it].x;
            As[kk + 1][msw] = av[it].y;
            As[kk + 2][msw] = av[it].z;
            As[kk + 3][msw] = av[it].w;
        }
#pragma unroll
        for (int it = 0; it < 4; ++it) {
            int q = tid + it * 256;
            ((float4*)&Bs[0][0])[q] = bv[it];
        }

        __syncthreads();

#pragma unroll
        for (int k = 0; k < 32; ++k) {
            int swz = (k >> 2) << 3;
            const float4* ap = (const float4*)&As[k][(ty * 8) ^ swz];
            float4 a0 = ap[0];
            float4 a1 = ap[1];
            float4 b  = ((const float4*)&Bs[k][0])[tx];
            float a[8] = {a0.x, a0.y, a0.z, a0.w, a1.x, a1.y, a1.z, a1.w};
            float bb[4] = {b.x, b.y, b.z, b.w};
#pragma unroll
            for (int i2 = 0; i2 < 8; ++i2)
#pragma unroll
                for (int j = 0; j < 4; ++j)
                    acc[i2][j] += a[i2] * bb[j];
        }
    }

#pragma unroll
    for (int i2 = 0; i2 < 8; ++i2) {
        int r = row0 + ty * 8 + i2;
        if (r < nNodes) {
            float4 v;
            v.x = fmaxf(acc[i2][0], 0.f);
            v.y = fmaxf(acc[i2][1], 0.f);
            v.z = fmaxf(acc[i2][2], 0.f);
            v.w = fmaxf(acc[i2][3], 0.f);
            ((float4*)(out + (size_t)r * D))[tx] = v;
        }
    }
}

extern "C" void kernel_launch(void* const* d_in, const int* in_sizes, int n_in,
                              void* d_out, int out_size, void* d_ws, size_t ws_size,
                              hipStream_t stream) {
    const float* x = (const float*)d_in[0];
    const float* W = (const float*)d_in[1];
    const float* M = (const float*)d_in[2];
    const int* edges = (const int*)d_in[3];

    int N  = in_sizes[0] / D;        // 50000
    int nE = in_sizes[3] / 2;        // 800000
    const int* src = edges;          // edges[0, :]
    const int* dst = edges + nE;     // edges[1, :]
    float* out = (float*)d_out;

    // workspace layout
    char* w = (char*)d_ws;
    float* s = (float*)w;            w += (size_t)N * D * sizeof(float);   // 25.6 MB
    int* hist = (int*)w;             w += (size_t)(N + 1) * sizeof(int);   // [N]=total
    int* beg = (int*)w;              w += (size_t)N * sizeof(int);
    int* cursor = (int*)w;           w += (size_t)N * sizeof(int);
    int* eidx = (int*)w;             w += (size_t)nE * sizeof(int);        // 3.2 MB
    int* total = hist + N;

    hipMemsetAsync(hist, 0, (size_t)(N + 1) * sizeof(int), stream);

    hist_k<<<(nE + 255) / 256, 256, 0, stream>>>(dst, nE, hist);
    reserve_k<<<(N + NTHREADS - 1) / NTHREADS, NTHREADS, 0, stream>>>(hist, N, beg, cursor, total);
    scatter_k<<<(nE + 255) / 256, 256, 0, stream>>>(src, dst, nE, cursor, eidx);

    int segBlocks = (N * 64 + 255) / 256;        // one wave per node
    segsum_k<<<segBlocks, 256, 0, stream>>>(x, beg, hist, eidx, s, N);

    int gemmBlocks = (N + 63) / 64;
    gemm2_k<<<gemmBlocks, 256, 0, stream>>>(x, s, W, M, out, N);
}

// Round 4
// 292.776 us; speedup vs baseline: 1.6215x; 1.0586x over previous
//
#include <hip/hip_runtime.h>

#define D 128
#define NTHREADS 256

// ---------- 1. histogram of dst ----------
__global__ void hist_k(const int* __restrict__ dst, int nE, int* __restrict__ hist) {
    int i = blockIdx.x * blockDim.x + threadIdx.x;
    if (i < nE) atomicAdd(&hist[dst[i]], 1);
}

// ---------- 2. reserve bucket ranges: block scan + single atomic bump ----------
// Bucket ORDER in eidx is irrelevant; only contiguity per dst matters.
__global__ void reserve_k(const int* __restrict__ hist, int n,
                          int* __restrict__ beg, int* __restrict__ cursor,
                          int* __restrict__ total) {
    __shared__ int wsum[4];
    __shared__ int sbase;
    int i = blockIdx.x * NTHREADS + threadIdx.x;
    int v = (i < n) ? hist[i] : 0;
    int lane = threadIdx.x & 63;
    int wid  = threadIdx.x >> 6;
    int incl = v;
#pragma unroll
    for (int off = 1; off < 64; off <<= 1) {
        int t = __shfl_up(incl, off, 64);
        if (lane >= off) incl += t;
    }
    if (lane == 63) wsum[wid] = incl;
    __syncthreads();
    if (threadIdx.x == 0)
        sbase = atomicAdd(total, wsum[0] + wsum[1] + wsum[2] + wsum[3]);
    __syncthreads();
    int wbase = sbase;
    for (int w = 0; w < wid; ++w) wbase += wsum[w];
    int excl = wbase + incl - v;
    if (i < n) { beg[i] = excl; cursor[i] = excl; }
}

// ---------- 3. scatter src ids into dst-buckets ----------
__global__ void scatter_k(const int* __restrict__ src, const int* __restrict__ dst,
                          int nE, int* __restrict__ cursor, int* __restrict__ eidx) {
    int i = blockIdx.x * blockDim.x + threadIdx.x;
    if (i < nE) {
        int p = atomicAdd(&cursor[dst[i]], 1);
        eidx[p] = src[i];
    }
}

// ---------- 4. wave-per-node segment sum with 4-deep ILP ----------
// s[i] = sum_{e: dst=i} x[src_e]; 64 lanes = one row (float2/lane).
// Unroll 4 with independent accumulators: 4 row-gathers in flight breaks
// the serial idx->gather dependency chain that made round-2 latency-bound.
__global__ void segsum_k(const float* __restrict__ x, const int* __restrict__ beg,
                         const int* __restrict__ hist, const int* __restrict__ eidx,
                         float* __restrict__ s, int nNodes) {
    int wave = (int)((blockIdx.x * (unsigned)blockDim.x + threadIdx.x) >> 6);
    int lane = threadIdx.x & 63;
    if (wave >= nNodes) return;
    int b = beg[wave];
    int e = b + hist[wave];
    const float2* x2 = (const float2*)x;
    float2 a0 = make_float2(0.f, 0.f), a1 = a0, a2 = a0, a3 = a0;
    int k = b;
    for (; k + 4 <= e; k += 4) {
        int j0 = eidx[k + 0];
        int j1 = eidx[k + 1];
        int j2 = eidx[k + 2];
        int j3 = eidx[k + 3];
        float2 v0 = x2[(size_t)j0 * 64 + lane];
        float2 v1 = x2[(size_t)j1 * 64 + lane];
        float2 v2 = x2[(size_t)j2 * 64 + lane];
        float2 v3 = x2[(size_t)j3 * 64 + lane];
        a0.x += v0.x; a0.y += v0.y;
        a1.x += v1.x; a1.y += v1.y;
        a2.x += v2.x; a2.y += v2.y;
        a3.x += v3.x; a3.y += v3.y;
    }
    for (; k < e; ++k) {
        int j = eidx[k];
        float2 v = x2[(size_t)j * 64 + lane];
        a0.x += v.x; a0.y += v.y;
    }
    a0.x += a1.x + a2.x + a3.x;
    a0.y += a1.y + a2.y + a3.y;
    ((float2*)(s + (size_t)wave * D))[lane] = a0;
}

// ---------- 5. out = relu([x|s] @ [W;M]) — BM=128 register-blocked GEMM ----------
// M=50000 rows, N=128 cols, K=256 (k<128 -> x@W, k>=128 -> s@M).
// 256 threads, 16x16 thread grid, 8x8 micro-tile. A tile k-major with XOR
// swizzle col = m ^ ((k>>2)<<3): staging writes 2-way (free), frag reads clean.
__global__ __launch_bounds__(NTHREADS) void gemm2_k(
    const float* __restrict__ x, const float* __restrict__ s,
    const float* __restrict__ W, const float* __restrict__ M,
    float* __restrict__ out, int nNodes)
{
    __shared__ float As[32][128];   // [k][m swizzled]
    __shared__ float Bs[32][128];   // [k][n] linear
    const int tid  = threadIdx.x;
    const int tx   = tid & 15;      // col group: cols tx*8 .. tx*8+7
    const int ty   = tid >> 4;      // row group: rows ty*8 .. ty*8+7
    const int row0 = blockIdx.x * 128;

    float acc[8][8];
#pragma unroll
    for (int i = 0; i < 8; ++i)
#pragma unroll
        for (int j = 0; j < 8; ++j) acc[i][j] = 0.f;

    for (int kt = 0; kt < 8; ++kt) {
        const int kb = kt * 32;
        const float* Asrc = (kb < 128) ? x : s;
        const float* Bsrc = (kb < 128) ? W : M;
        const int ak = kb & 127;

        // register-stage A (128 rows x 32 k): 4 float4/thread
        float4 av[4];
        int mm[4], kk4[4];
#pragma unroll
        for (int it = 0; it < 4; ++it) {
            int q = tid + it * 256;           // 0..1023
            int m = q >> 3, k4 = q & 7;       // m 0..127, k4 0..7
            mm[it] = m; kk4[it] = k4;
            int r = row0 + m;
            float4 v = make_float4(0.f, 0.f, 0.f, 0.f);
            if (r < nNodes) v = ((const float4*)(Asrc + (size_t)r * D + ak))[k4];
            av[it] = v;
        }
        // register-stage B (32 rows x 128 cols): 4 float4/thread, coalesced
        float4 bv[4];
#pragma unroll
        for (int it = 0; it < 4; ++it) {
            int q = tid + it * 256;           // 0..1023
            int rr = q >> 5, c4 = q & 31;
            bv[it] = ((const float4*)(Bsrc + (size_t)(ak + rr) * D))[c4];
        }

        __syncthreads();   // previous iteration's compute done before overwrite

#pragma unroll
        for (int it = 0; it < 4; ++it) {
            int msw = mm[it] ^ (kk4[it] << 3);
            int kk  = kk4[it] * 4;
            As[kk + 0][msw] = av[it].x;
            As[kk + 1][msw] = av[it].y;
            As[kk + 2][msw] = av[it].z;
            As[kk + 3][msw] = av[it].w;
        }
#pragma unroll
        for (int it = 0; it < 4; ++it) {
            int q = tid + it * 256;
            ((float4*)&Bs[0][0])[q] = bv[it];
        }

        __syncthreads();

#pragma unroll
        for (int k = 0; k < 32; ++k) {
            int swz = (k >> 2) << 3;
            const float4* ap = (const float4*)&As[k][(ty * 8) ^ swz];
            float4 a0 = ap[0];
            float4 a1 = ap[1];
            const float4* bp = (const float4*)&Bs[k][tx * 8];
            float4 b0 = bp[0];
            float4 b1 = bp[1];
            float a[8]  = {a0.x, a0.y, a0.z, a0.w, a1.x, a1.y, a1.z, a1.w};
            float bb[8] = {b0.x, b0.y, b0.z, b0.w, b1.x, b1.y, b1.z, b1.w};
#pragma unroll
            for (int i2 = 0; i2 < 8; ++i2)
#pragma unroll
                for (int j = 0; j < 8; ++j)
                    acc[i2][j] += a[i2] * bb[j];
        }
    }

#pragma unroll
    for (int i2 = 0; i2 < 8; ++i2) {
        int r = row0 + ty * 8 + i2;
        if (r < nNodes) {
            float4 v0, v1;
            v0.x = fmaxf(acc[i2][0], 0.f);
            v0.y = fmaxf(acc[i2][1], 0.f);
            v0.z = fmaxf(acc[i2][2], 0.f);
            v0.w = fmaxf(acc[i2][3], 0.f);
            v1.x = fmaxf(acc[i2][4], 0.f);
            v1.y = fmaxf(acc[i2][5], 0.f);
            v1.z = fmaxf(acc[i2][6], 0.f);
            v1.w = fmaxf(acc[i2][7], 0.f);
            ((float4*)(out + (size_t)r * D))[tx * 2 + 0] = v0;
            ((float4*)(out + (size_t)r * D))[tx * 2 + 1] = v1;
        }
    }
}

extern "C" void kernel_launch(void* const* d_in, const int* in_sizes, int n_in,
                              void* d_out, int out_size, void* d_ws, size_t ws_size,
                              hipStream_t stream) {
    const float* x = (const float*)d_in[0];
    const float* W = (const float*)d_in[1];
    const float* M = (const float*)d_in[2];
    const int* edges = (const int*)d_in[3];

    int N  = in_sizes[0] / D;        // 50000
    int nE = in_sizes[3] / 2;        // 800000
    const int* src = edges;          // edges[0, :]
    const int* dst = edges + nE;     // edges[1, :]
    float* out = (float*)d_out;

    // workspace layout
    char* w = (char*)d_ws;
    float* s = (float*)w;            w += (size_t)N * D * sizeof(float);   // 25.6 MB
    int* hist = (int*)w;             w += (size_t)(N + 1) * sizeof(int);   // [N]=total
    int* beg = (int*)w;              w += (size_t)N * sizeof(int);
    int* cursor = (int*)w;           w += (size_t)N * sizeof(int);
    int* eidx = (int*)w;             w += (size_t)nE * sizeof(int);        // 3.2 MB

    int* total = hist + N;

    hipMemsetAsync(hist, 0, (size_t)(N + 1) * sizeof(int), stream);

    hist_k<<<(nE + 255) / 256, 256, 0, stream>>>(dst, nE, hist);
    reserve_k<<<(N + NTHREADS - 1) / NTHREADS, NTHREADS, 0, stream>>>(hist, N, beg, cursor, total);
    scatter_k<<<(nE + 255) / 256, 256, 0, stream>>>(src, dst, nE, cursor, eidx);

    int segBlocks = (N * 64 + 255) / 256;        // one wave per node
    segsum_k<<<segBlocks, 256, 0, stream>>>(x, beg, hist, eidx, s, N);

    int gemmBlocks = (N + 127) / 128;
    gemm2_k<<<gemmBlocks, 256, 0, stream>>>(x, s, W, M, out, N);
}

// Round 6
// 242.729 us; speedup vs baseline: 1.9558x; 1.2062x over previous
//
#include <hip/hip_runtime.h>

#define D 128
#define NTHREADS 256

typedef __attribute__((ext_vector_type(8))) short short8;
typedef __attribute__((ext_vector_type(8))) unsigned short ushort8;
typedef __attribute__((ext_vector_type(4))) float f32x4;

// round-to-nearest-even f32 -> bf16 bits
__device__ __forceinline__ unsigned short f2bf(float f) {
    unsigned u = __float_as_uint(f);
    unsigned r = (u + 0x7fffu + ((u >> 16) & 1u)) >> 16;
    return (unsigned short)r;
}

// ---------- 1. histogram of dst ----------
__global__ void hist_k(const int* __restrict__ dst, int nE, int* __restrict__ hist) {
    int i = blockIdx.x * blockDim.x + threadIdx.x;
    if (i < nE) atomicAdd(&hist[dst[i]], 1);
}

// ---------- 2. reserve bucket ranges: block scan + single atomic bump ----------
__global__ void reserve_k(const int* __restrict__ hist, int n,
                          int* __restrict__ beg, int* __restrict__ cursor,
                          int* __restrict__ total) {
    __shared__ int wsum[4];
    __shared__ int sbase;
    int i = blockIdx.x * NTHREADS + threadIdx.x;
    int v = (i < n) ? hist[i] : 0;
    int lane = threadIdx.x & 63;
    int wid  = threadIdx.x >> 6;
    int incl = v;
#pragma unroll
    for (int off = 1; off < 64; off <<= 1) {
        int t = __shfl_up(incl, off, 64);
        if (lane >= off) incl += t;
    }
    if (lane == 63) wsum[wid] = incl;
    __syncthreads();
    if (threadIdx.x == 0)
        sbase = atomicAdd(total, wsum[0] + wsum[1] + wsum[2] + wsum[3]);
    __syncthreads();
    int wbase = sbase;
    for (int w = 0; w < wid; ++w) wbase += wsum[w];
    int excl = wbase + incl - v;
    if (i < n) { beg[i] = excl; cursor[i] = excl; }
}

// ---------- 3. scatter src ids into dst-buckets ----------
__global__ void scatter_k(const int* __restrict__ src, const int* __restrict__ dst,
                          int nE, int* __restrict__ cursor, int* __restrict__ eidx) {
    int i = blockIdx.x * blockDim.x + threadIdx.x;
    if (i < nE) {
        int p = atomicAdd(&cursor[dst[i]], 1);
        eidx[p] = src[i];
    }
}

// ---------- 4. wave-per-node segment sum with 4-deep ILP ----------
__global__ void segsum_k(const float* __restrict__ x, const int* __restrict__ beg,
                         const int* __restrict__ hist, const int* __restrict__ eidx,
                         float* __restrict__ s, int nNodes) {
    int wave = (int)((blockIdx.x * (unsigned)blockDim.x + threadIdx.x) >> 6);
    int lane = threadIdx.x & 63;
    if (wave >= nNodes) return;
    int b = beg[wave];
    int e = b + hist[wave];
    const float2* x2 = (const float2*)x;
    float2 a0 = make_float2(0.f, 0.f), a1 = a0, a2 = a0, a3 = a0;
    int k = b;
    for (; k + 4 <= e; k += 4) {
        int j0 = eidx[k + 0];
        int j1 = eidx[k + 1];
        int j2 = eidx[k + 2];
        int j3 = eidx[k + 3];
        float2 v0 = x2[(size_t)j0 * 64 + lane];
        float2 v1 = x2[(size_t)j1 * 64 + lane];
        float2 v2 = x2[(size_t)j2 * 64 + lane];
        float2 v3 = x2[(size_t)j3 * 64 + lane];
        a0.x += v0.x; a0.y += v0.y;
        a1.x += v1.x; a1.y += v1.y;
        a2.x += v2.x; a2.y += v2.y;
        a3.x += v3.x; a3.y += v3.y;
    }
    for (; k < e; ++k) {
        int j = eidx[k];
        float2 v = x2[(size_t)j * 64 + lane];
        a0.x += v.x; a0.y += v.y;
    }
    a0.x += a1.x + a2.x + a3.x;
    a0.y += a1.y + a2.y + a3.y;
    ((float2*)(s + (size_t)wave * D))[lane] = a0;
}

// ---------- 5a. prepass: B^T bf16. BT[col][k], k-contiguous per col ----------
// B = [W;M] stacked ([256][128] f32 k-major). BT element = BT[col*256 + k].
__global__ void bt_k(const float* __restrict__ W, const float* __restrict__ M,
                     unsigned short* __restrict__ BT) {
    int g = blockIdx.x * 256 + threadIdx.x;     // 0..4095
    int col = g >> 5;
    int k0  = (g & 31) * 8;
    ushort8 hv;
#pragma unroll
    for (int j = 0; j < 8; ++j) {
        int k = k0 + j;
        float v = (k < 128) ? W[k * 128 + col] : M[(k - 128) * 128 + col];
        hv[j] = f2bf(v);
    }
    *(ushort8*)(BT + col * 256 + k0) = hv;
}

// ---------- 5b. out = relu([x|s] @ [W;M]) via single-pass bf16 MFMA ----------
// Threshold is bf16-grade (6.16; exact f32 scored 0.5), so single-pass bf16 is
// numerically safe (predicted absmax ~1). 16x16x32 bf16 MFMA.
// Block: 64 rows x 128 cols, 4 waves; wave = 64 rows x 32 cols (4 rowgrp x 2 colgrp).
// A tile (bf16, full K=256) in LDS, XOR-swizzled: byte ^= (row&7)<<4 (m214 G4 fix).
// B-frags read straight from global BT (L2-hot, 64 KB shared by all blocks).
__global__ __launch_bounds__(NTHREADS, 2) void gemm_mfma_k(
    const float* __restrict__ x, const float* __restrict__ s,
    const unsigned short* __restrict__ BT,
    float* __restrict__ out, int nNodes)
{
    __shared__ unsigned short Alds[64 * 256];   // [row][k] bf16, 32 KB
    char* Ab = (char*)Alds;

    const int tid  = threadIdx.x;
    const int lane = tid & 63;
    const int wv   = tid >> 6;          // 0..3
    const int r0   = blockIdx.x * 64;
    const int wcol = wv * 32;

    // ---- stage A = [x | s] rows r0..r0+63, f32 -> bf16, swizzled LDS ----
    // 64 rows x 128 k per half = 2048 float4 slots; 256 threads x 8 iters.
#pragma unroll
    for (int h = 0; h < 2; ++h) {
        const float* src = h ? s : x;
#pragma unroll
        for (int it = 0; it < 8; ++it) {
            int q   = tid + it * 256;          // 0..2047
            int row = q >> 5;                  // 0..63
            int kin = (q & 31) * 4;            // 0..124
            float4 v = make_float4(0.f, 0.f, 0.f, 0.f);
            if (r0 + row < nNodes)
                v = *(const float4*)(src + (size_t)(r0 + row) * D + kin);
            ushort4 hv = make_ushort4(f2bf(v.x), f2bf(v.y), f2bf(v.z), f2bf(v.w));
            int byte = (row * 512 + (h * 128 + kin) * 2) ^ ((row & 7) << 4);
            *(ushort4*)(Ab + byte) = hv;
        }
    }
    __syncthreads();

    f32x4 acc[4][2];
#pragma unroll
    for (int rg = 0; rg < 4; ++rg)
#pragma unroll
        for (int cg = 0; cg < 2; ++cg)
            acc[rg][cg] = (f32x4){0.f, 0.f, 0.f, 0.f};

    const int l16  = lane & 15;
    const int lk8  = (lane >> 4) * 8;

    // ---- K loop: 8 steps of 32, fully unrolled ----
#pragma unroll
    for (int t = 0; t < 8; ++t) {
        // B fragments from global (L2-hot)
        short8 bh[2];
#pragma unroll
        for (int cg = 0; cg < 2; ++cg) {
            int col = wcol + cg * 16 + l16;
            bh[cg] = *(const short8*)(BT + col * 256 + t * 32 + lk8);
        }
        // A fragments from LDS
        short8 ah[4];
#pragma unroll
        for (int rg = 0; rg < 4; ++rg) {
            int row  = rg * 16 + l16;
            int byte = (row * 512 + (t * 32 + lk8) * 2) ^ ((row & 7) << 4);
            ah[rg] = *(const short8*)(Ab + byte);
        }
#pragma unroll
        for (int rg = 0; rg < 4; ++rg)
#pragma unroll
            for (int cg = 0; cg < 2; ++cg)
                acc[rg][cg] = __builtin_amdgcn_mfma_f32_16x16x32_bf16(ah[rg], bh[cg], acc[rg][cg], 0, 0, 0);
    }

    // ---- epilogue: relu + store. D layout: col = lane&15, row = (lane>>4)*4 + reg ----
    const int rowoff = (lane >> 4) * 4;
#pragma unroll
    for (int rg = 0; rg < 4; ++rg) {
#pragma unroll
        for (int r = 0; r < 4; ++r) {
            int row = r0 + rg * 16 + rowoff + r;
            if (row < nNodes) {
#pragma unroll
                for (int cg = 0; cg < 2; ++cg) {
                    float v = acc[rg][cg][r];
                    out[(size_t)row * D + wcol + cg * 16 + l16] = v > 0.f ? v : 0.f;
                }
            }
        }
    }
}

extern "C" void kernel_launch(void* const* d_in, const int* in_sizes, int n_in,
                              void* d_out, int out_size, void* d_ws, size_t ws_size,
                              hipStream_t stream) {
    const float* x = (const float*)d_in[0];
    const float* W = (const float*)d_in[1];
    const float* M = (const float*)d_in[2];
    const int* edges = (const int*)d_in[3];

    int N  = in_sizes[0] / D;        // 50000
    int nE = in_sizes[3] / 2;        // 800000
    const int* src = edges;          // edges[0, :]
    const int* dst = edges + nE;     // edges[1, :]
    float* out = (float*)d_out;

    // workspace layout
    char* w = (char*)d_ws;
    float* s = (float*)w;            w += (size_t)N * D * sizeof(float);   // 25.6 MB
    int* hist = (int*)w;             w += (size_t)(N + 1) * sizeof(int);   // [N]=total
    int* beg = (int*)w;              w += (size_t)N * sizeof(int);
    int* cursor = (int*)w;           w += (size_t)N * sizeof(int);
    int* eidx = (int*)w;             w += (size_t)nE * sizeof(int);        // 3.2 MB
    unsigned short* BT = (unsigned short*)w; w += 32768 * sizeof(unsigned short); // 64 KB

    int* total = hist + N;

    hipMemsetAsync(hist, 0, (size_t)(N + 1) * sizeof(int), stream);

    bt_k<<<16, 256, 0, stream>>>(W, M, BT);
    hist_k<<<(nE + 255) / 256, 256, 0, stream>>>(dst, nE, hist);
    reserve_k<<<(N + NTHREADS - 1) / NTHREADS, NTHREADS, 0, stream>>>(hist, N, beg, cursor, total);
    scatter_k<<<(nE + 255) / 256, 256, 0, stream>>>(src, dst, nE, cursor, eidx);

    int segBlocks = (N * 64 + 255) / 256;        // one wave per node
    segsum_k<<<segBlocks, 256, 0, stream>>>(x, beg, hist, eidx, s, N);

    int gemmBlocks = (N + 63) / 64;              // 782
    gemm_mfma_k<<<gemmBlocks, 256, 0, stream>>>(x, s, BT, out, N);
}